// Round 9
// baseline (233.890 us; speedup 1.0000x reference)
//
#include <hip/hip_runtime.h>
#include <math.h>

#define DIM     4096
#define NEXP    64
#define TOPK_N  8
#define TAU     2.0e-4f
#define TGB     64                  // tokens per gemm block (4 waves x 16)
#define KC      512                 // k-chunk per gemm block
#define NKC     (DIM / KC)          // 8 chunks
#define NST     (KC / 32)           // 16 k32 subtiles per chunk

typedef __attribute__((ext_vector_type(8))) short short8;   // 8 bf16
typedef __attribute__((ext_vector_type(4))) float f32x4;

#define WALL __builtin_amdgcn_sched_barrier(0)

// fp32 -> bf16 hi (trunc) + bf16 lo (trunc of exact residual)
__device__ __forceinline__ void cvt8(float4 a0, float4 a1, short8& hv, short8& lv) {
    float f[8] = {a0.x, a0.y, a0.z, a0.w, a1.x, a1.y, a1.z, a1.w};
    union { short8 v; unsigned u[4]; } H, L;
    #pragma unroll
    for (int i = 0; i < 4; ++i) {
        unsigned b0 = __float_as_uint(f[2*i]);
        unsigned b1 = __float_as_uint(f[2*i+1]);
        float r0 = f[2*i]   - __uint_as_float(b0 & 0xffff0000u);
        float r1 = f[2*i+1] - __uint_as_float(b1 & 0xffff0000u);
        H.u[i] = (b0 >> 16) | (b1 & 0xffff0000u);
        L.u[i] = (__float_as_uint(r0) >> 16) | (__float_as_uint(r1) & 0xffff0000u);
    }
    hv = H.v; lv = L.v;
}

// async global->LDS, 16B per lane; LDS dest = wave-uniform base + lane*16 (linear);
// global source address is fully per-lane.
__device__ __forceinline__ void async16(void* lds, const void* g) {
    __builtin_amdgcn_global_load_lds(
        (const __attribute__((address_space(1))) unsigned int*)g,
        (__attribute__((address_space(3))) unsigned int*)lds, 16, 0, 0);
}

// ---------------- Pass 0 (atomic mode only): zero the score accumulator ----------------
__global__ __launch_bounds__(256, 4)
void zero_kernel(float* __restrict__ p) {
    const size_t g = (size_t)blockIdx.x * 256 + threadIdx.x;
    *(float4*)(p + g * 4) = (float4){0.f, 0.f, 0.f, 0.f};
}

// ---------------- Pass 1: split-K GEMM, gll-staged, T3/T4 counted-vmcnt pipeline ----------
// 1024 blocks x 256 thr (4 waves). Block = 64 tokens x 64 experts x k-chunk 512.
// Both A (x, fp32) and B (w, fp32 -- cvt8 to bf16 hi/lo in-compute, bit-identical to the
// old cvt_w precompute) staged via global_load_lds: rows of 128 B (32 fp32), XOR-swizzled
// (row&7)<<4 on the SOURCE at stage time and on the ds_read (rule-21 involution).
// 3 LDS buffers; ONE raw s_barrier per subtile; counted s_waitcnt vmcnt(4) (2 STAGEs of
// 4 gll/wave in flight, drain only the oldest) -- never vmcnt(0) in the main loop (T4).
// STAGE(st+2) issues BEFORE COMPUTE(st): each load gets ~2 compute phases to land.
// Overwrite safety: buf b staged at iter k is re-staged at iter k+1 only after barrier(k+1),
// by which point all waves finished COMPUTE(k) (3-buffer rotation).
template<int USE_PART>
__global__ __launch_bounds__(256, 3)
void gemm_part_kernel(const float* __restrict__ x, const float* __restrict__ w,
                      float* __restrict__ dst, int ntok) {
    __shared__ float A_lds[3][TGB][32];    // 3 x 8 KB
    __shared__ float B_lds[3][NEXP][32];   // 3 x 8 KB

    const int tid  = threadIdx.x;
    const int lane = tid & 63;
    const int wv   = tid >> 6;
    const int nl   = lane & 15;
    const int q    = lane >> 4;
    const int kc   = blockIdx.x & (NKC - 1);
    const int tg   = blockIdx.x >> 3;
    const int t0b  = tg * TGB;
    const int k0   = kc * KC;

    // staging constants: per STAGE each wave issues 2 A-insts + 2 B-insts (4 gll).
    // inst i covers 8 rows x 128 B; dest linear, source pre-XOR'd with row swizzle.
    int arow[2];
    const float* gA[2];
    const float* gB[2];
    #pragma unroll
    for (int i = 0; i < 2; ++i) {
        const int inst = wv * 2 + i;
        const int r    = inst * 8 + (lane >> 3);                 // row within tile
        const int scb  = ((lane & 7) * 16) ^ ((r & 7) << 4);     // swizzled byte-in-row
        arow[i] = inst * 8;
        gA[i] = x + (size_t)(t0b + r) * DIM + k0 + (scb >> 2);
        gB[i] = w + (size_t)r * DIM + k0 + (scb >> 2);           // expert row r
    }

    f32x4 acc[4];
    #pragma unroll
    for (int nf = 0; nf < 4; ++nf) acc[nf] = (f32x4){0.f, 0.f, 0.f, 0.f};

#define STAGE(b_, st_) do {                                                    \
        async16(&A_lds[b_][arow[0]][0], gA[0] + (st_) * 32);                   \
        async16(&A_lds[b_][arow[1]][0], gA[1] + (st_) * 32);                   \
        async16(&B_lds[b_][arow[0]][0], gB[0] + (st_) * 32);                   \
        async16(&B_lds[b_][arow[1]][0], gB[1] + (st_) * 32);                   \
    } while (0)

#define COMPUTE(b_) do {                                                       \
        const int swz_ = (nl & 7) << 4;                                        \
        const char* Ab_ = (const char*)&A_lds[b_][wv * 16 + nl][0];            \
        float4 a0_ = *(const float4*)(Ab_ + ((q * 32) ^ swz_));                \
        float4 a1_ = *(const float4*)(Ab_ + ((q * 32 + 16) ^ swz_));           \
        short8 ahi_, alo_;                                                     \
        cvt8(a0_, a1_, ahi_, alo_);                                            \
        _Pragma("unroll")                                                      \
        for (int nf_ = 0; nf_ < 4; ++nf_) {                                    \
            const char* Bb_ = (const char*)&B_lds[b_][nf_ * 16 + nl][0];       \
            float4 b0_ = *(const float4*)(Bb_ + ((q * 32) ^ swz_));            \
            float4 b1_ = *(const float4*)(Bb_ + ((q * 32 + 16) ^ swz_));       \
            short8 bh_, bl_;                                                   \
            cvt8(b0_, b1_, bh_, bl_);                                          \
            acc[nf_] = __builtin_amdgcn_mfma_f32_16x16x32_bf16(ahi_, bl_, acc[nf_], 0, 0, 0); \
            acc[nf_] = __builtin_amdgcn_mfma_f32_16x16x32_bf16(alo_, bh_, acc[nf_], 0, 0, 0); \
            acc[nf_] = __builtin_amdgcn_mfma_f32_16x16x32_bf16(ahi_, bh_, acc[nf_], 0, 0, 0); \
        }                                                                      \
    } while (0)

    // prologue: two STAGEs in flight (8 outstanding gll per wave)
    STAGE(0, 0);
    STAGE(1, 1);
    #pragma unroll 1
    for (int st = 0; st < NST; ++st) {
        // drain only the OLDEST stage (4 loads); keep the other 4 in flight (T4)
        if (st < NST - 1) {
            asm volatile("s_waitcnt vmcnt(4)" ::: "memory");
        } else {
            asm volatile("s_waitcnt vmcnt(0)" ::: "memory");
        }
        __builtin_amdgcn_s_barrier();
        __builtin_amdgcn_sched_barrier(0);      // rule 18: no hoisting above the wait
        if (st + 2 < NST) STAGE((st + 2) % 3, st + 2);   // issue early: 2 phases of cover
        WALL;
        COMPUTE(st % 3);
    }

#undef STAGE
#undef COMPUTE

    // C/D layout (verified): col = lane&15 -> expert, row = q*4+r -> token-in-wave-group
    #pragma unroll
    for (int nf = 0; nf < 4; ++nf)
        #pragma unroll
        for (int r = 0; r < 4; ++r) {
            const int tok = t0b + wv * 16 + q * 4 + r;
            const int e   = nf * 16 + nl;
            if (USE_PART)
                dst[((size_t)tok * NKC + kc) * NEXP + e] = acc[nf][r];
            else
                atomicAdd(&dst[(size_t)tok * NEXP + e], acc[nf][r]);
        }
}

// ---------------- Pass 2: reduce + softmax + top-8 + fp64 recheck (wave-local) ----------------
// 2048 blocks x 256 thr; wave = one token, lane = expert. No __syncthreads anywhere.
template<int USE_PART>
__global__ __launch_bounds__(256, 4)
void finish_kernel(const float* __restrict__ src, const float* __restrict__ bias,
                   const float* __restrict__ x, const float* __restrict__ wfp,
                   float* __restrict__ out, int ntok) {
    __shared__ float lds_s[4][68];   // per-wave score row (16B-aligned rows)
    __shared__ float t9[4][12];      // per-wave top-9

    const int tid  = threadIdx.x;
    const int lane = tid & 63;
    const int wv   = tid >> 6;
    const int tok  = blockIdx.x * 4 + wv;

    float s;
    if (USE_PART) {
        // fixed-order reduce of NKC chunk partials (deterministic)
        const float* pr = src + (size_t)tok * NKC * NEXP;
        s = pr[lane];
        #pragma unroll
        for (int c = 1; c < NKC; ++c) s += pr[c * NEXP + lane];
    } else {
        s = src[(size_t)tok * NEXP + lane];   // atomically accumulated score
    }
    s += bias[lane];

    // softmax (butterfly)
    float m = s;
    #pragma unroll
    for (int off = 32; off > 0; off >>= 1)
        m = fmaxf(m, __shfl_xor(m, off, 64));
    const float ex = expf(s - m);
    float sum = ex;
    #pragma unroll
    for (int off = 32; off > 0; off >>= 1)
        sum += __shfl_xor(sum, off, 64);
    out[(size_t)tok * NEXP + lane] = ex / sum;

    // parallel rank via wave-local LDS row (intra-wave lockstep, no barrier needed)
    lds_s[wv][lane] = s;
    int rank = 0;
    #pragma unroll
    for (int i = 0; i < 16; ++i) {
        const float4 v4 = *(const float4*)(&lds_s[wv][i * 4]);
        rank += (int)((v4.x > s) || (v4.x == s && (i * 4 + 0) < lane));
        rank += (int)((v4.y > s) || (v4.y == s && (i * 4 + 1) < lane));
        rank += (int)((v4.z > s) || (v4.z == s && (i * 4 + 2) < lane));
        rank += (int)((v4.w > s) || (v4.w == s && (i * 4 + 3) < lane));
    }
    float* __restrict__ out_idx = out + (size_t)ntok * NEXP;
    if (rank < TOPK_N + 1) t9[wv][rank] = s;
    if (rank < TOPK_N)
        out_idx[(size_t)tok * TOPK_N + rank] = (float)lane;

    // tie-screen on the 8 gaps of the top-9 (wave-local)
    float gap = 1e30f;
    if (lane < TOPK_N) gap = t9[wv][lane] - t9[wv][lane + 1];
    if (__any(gap < TAU)) {
        // fp64 recheck: candidates = scores >= 9th-best - TAU (deterministic result)
        const float thr = t9[wv][TOPK_N] - TAU;
        const unsigned long long cmask = __ballot(s >= thr);
        double dscv = -1.0e300;
        unsigned long long mm = cmask;
        while (mm) {
            const int e = __builtin_ctzll(mm);
            mm &= mm - 1;
            const float* wr  = wfp + (size_t)e * DIM;
            const float* xrr = x + (size_t)tok * DIM;
            double a = 0.0;
            #pragma unroll 4
            for (int kk = 0; kk < 16; ++kk) {
                const int k = kk * 256 + lane * 4;
                const float4 wv4 = *(const float4*)(wr + k);
                const float4 xv  = *(const float4*)(xrr + k);
                a = fma((double)xv.x, (double)wv4.x, a);
                a = fma((double)xv.y, (double)wv4.y, a);
                a = fma((double)xv.z, (double)wv4.z, a);
                a = fma((double)xv.w, (double)wv4.w, a);
            }
            #pragma unroll
            for (int off = 32; off > 0; off >>= 1)
                a += __shfl_xor(a, off, 64);   // sum lands on all lanes
            a += (double)bias[e];
            if (lane == e) dscv = a;           // non-candidates stay -1e300
        }
        // serial argmax top-8 by fp64 score (rare path)
        double cv = dscv;
        for (int r = 0; r < TOPK_N; ++r) {
            double bv = cv;
            int    bi = lane;
            #pragma unroll
            for (int off = 32; off > 0; off >>= 1) {
                const double ov = __shfl_xor(bv, off, 64);
                const int    oi = __shfl_xor(bi, off, 64);
                if (ov > bv || (ov == bv && oi < bi)) { bv = ov; bi = oi; }
            }
            if (lane == r)
                out_idx[(size_t)tok * TOPK_N + r] = (float)bi;
            if (lane == bi) cv = -1.0e301;
        }
    }
}

extern "C" void kernel_launch(void* const* d_in, const int* in_sizes, int n_in,
                              void* d_out, int out_size, void* d_ws, size_t ws_size,
                              hipStream_t stream) {
    const float* x  = (const float*)d_in[0];
    const float* w  = (const float*)d_in[1];
    const float* bs = (const float*)d_in[2];
    float* out = (float*)d_out;

    const int ntok = in_sizes[0] / DIM;          // 8192

    const size_t part_need = (size_t)ntok * NKC * NEXP * sizeof(float);   // 16 MB
    if (ws_size >= part_need) {
        // deterministic split-K partials in workspace
        float* part = (float*)d_ws;
        hipLaunchKernelGGL((gemm_part_kernel<1>), dim3((ntok / TGB) * NKC), dim3(256), 0, stream,
                           x, w, part, ntok);
        hipLaunchKernelGGL((finish_kernel<1>), dim3(ntok / 4), dim3(256), 0, stream,
                           part, bs, x, w, out, ntok);
    } else {
        // workspace too small: accumulate scores atomically in out's probs region
        hipLaunchKernelGGL(zero_kernel, dim3((ntok * NEXP) / 1024), dim3(256), 0, stream, out);
        hipLaunchKernelGGL((gemm_part_kernel<0>), dim3((ntok / TGB) * NKC), dim3(256), 0, stream,
                           x, w, out, ntok);
        hipLaunchKernelGGL((finish_kernel<0>), dim3(ntok / 4), dim3(256), 0, stream,
                           out, bs, x, w, out, ntok);
    }
}